// Round 2
// baseline (273.009 us; speedup 1.0000x reference)
//
#include <hip/hip_runtime.h>
#include <cstddef>

#define BH 4
#define CH 64
#define OH 64
#define HH 128
#define WW 128
#define KK 9
#define KDIM (CH * KK)   // 576
#define HW (HH * WW)     // 16384

typedef __attribute__((ext_vector_type(8))) short short8;   // 8 bf16 (4 VGPRs)
typedef __attribute__((ext_vector_type(4))) float f32x4;    // MFMA acc

__device__ __forceinline__ unsigned short f2bf(float f) {
    unsigned u = __float_as_uint(f);
    u += 0x7fffu + ((u >> 16) & 1u);   // round-to-nearest-even
    return (unsigned short)(u >> 16);
}
__device__ __forceinline__ float bf2f(unsigned short h) {
    return __uint_as_float(((unsigned)h) << 16);
}

// ---------------------------------------------------------------------------
// Transpose x[b][c][h][w] f32 -> xt[b][h][w][c] bf16
// ---------------------------------------------------------------------------
__global__ __launch_bounds__(256) void dcl_transpose(const float* __restrict__ x,
                                                     unsigned short* __restrict__ xt) {
    __shared__ float tile[64][65];
    int chunk = blockIdx.x;              // 0 .. B*HW/64-1 = 1023
    int b = chunk >> 8;
    int hw0 = (chunk & 255) * 64;
    int tx = threadIdx.x;                // 0..63
    int ty = threadIdx.y;                // 0..3
    const float* xb = x + (size_t)b * CH * HW;
    for (int c = ty; c < 64; c += 4)
        tile[c][tx] = xb[(size_t)c * HW + hw0 + tx];
    __syncthreads();
    unsigned short* xtb = xt + ((size_t)b << 20);   // b*HW*CH
    for (int i = ty; i < 64; i += 4)
        xtb[(size_t)(hw0 + i) * CH + tx] = f2bf(tile[tx][i]);
}

// ---------------------------------------------------------------------------
// Pack weight[o][c][t] f32 -> wtb: B fragments for mfma_f32_16x16x32_bf16.
// frag f = ks*4 + nt (ks=0..17 k-steps of 32, nt=0..3 n-tiles of 16)
// lane l holds B[k][n] for k = ks*32 + (l>>4)*8 + j (j=0..7), n = nt*16 + (l&15)
// with k = t*64 + c.  Element addr: wtb[(f*64 + l)*8 + j]
// ---------------------------------------------------------------------------
__global__ __launch_bounds__(256) void dcl_wpack(const float* __restrict__ wgt,
                                                 unsigned short* __restrict__ wtb) {
    int idx = blockIdx.x * 256 + threadIdx.x;   // 0 .. 18*4*64*8-1 = 36863
    int j  = idx & 7;
    int l  = (idx >> 3) & 63;
    int nt = (idx >> 9) & 3;
    int ks = idx >> 11;
    int k = ks * 32 + ((l >> 4) * 8) + j;
    int n = nt * 16 + (l & 15);
    int c = k & 63;
    int t = k >> 6;
    wtb[idx] = f2bf(wgt[(n * CH + c) * KK + t]);
}

// ---------------------------------------------------------------------------
// Main kernel: wave = 16 pixels, block = 4 waves = 64 pixels.
// K split into 3 chunks of 3 taps (192 k) to keep LDS small (occupancy).
// Per chunk: gather -> wave-private LDS A-tile (bf16) -> 6 k-steps x 4 MFMA.
// ---------------------------------------------------------------------------
#define TPC 3                         // taps per chunk
#define NCHUNK 3
#define CHUNK_K (TPC * 64)            // 192
#define ROW_BF (CHUNK_K + 8)          // 200 bf16 (+8 pad: row stride 400 B)
#define WAVE_BYTES 6432               // 16*200*2=6400, padded to stagger banks

__global__ __launch_bounds__(256, 4) void dcl_main(
        const unsigned short* __restrict__ xt,   // [b][h][w][c] bf16
        const float* __restrict__ offset,
        const unsigned short* __restrict__ wtb,  // packed B fragments
        const float* __restrict__ bias,
        float* __restrict__ out) {
    __shared__ unsigned char smem[4 * WAVE_BYTES];
    int tid = threadIdx.x;
    int lane = tid & 63;
    int wave = tid >> 6;
    unsigned short* s_w = (unsigned short*)(smem + wave * WAVE_BYTES);

    int P0 = blockIdx.x * 64 + wave * 16;
    int m = lane & 15;
    int quad = lane >> 4;

    f32x4 acc[4];
#pragma unroll
    for (int i = 0; i < 4; ++i) acc[i] = (f32x4)(0.f);

    const short8* bfrags = (const short8*)wtb;

    for (int ch = 0; ch < NCHUNK; ++ch) {
        // ---- gather 3 taps x 16 pixels into wave-private A-tile ----
#pragma unroll 2
        for (int p = 0; p < 16; ++p) {
            int P = P0 + p;
            int b = P >> 14;
            int rem = P & (HW - 1);
            int y = rem >> 7;
            int x = rem & 127;
            const float* offb = offset + (size_t)b * 18 * HW + rem;
            const unsigned short* xb = xt + ((size_t)b << 20);
#pragma unroll
            for (int tl = 0; tl < TPC; ++tl) {
                int t = ch * TPC + tl;
                float ox = offb[(size_t)(2 * t) * HW];
                float oy = offb[(size_t)(2 * t + 1) * HW];
                float px = (float)x + ox;
                float py = (float)y + oy;
                float x0f = floorf(px), y0f = floorf(py);
                float wx1 = px - x0f, wy1 = py - y0f;
                float wx0 = 1.0f - wx1, wy0 = 1.0f - wy1;
                int ix0 = (int)x0f, iy0 = (int)y0f;
                int ix1 = ix0 + 1, iy1 = iy0 + 1;
                bool vx0 = (unsigned)ix0 < (unsigned)WW;
                bool vx1 = (unsigned)ix1 < (unsigned)WW;
                bool vy0 = (unsigned)iy0 < (unsigned)HH;
                bool vy1 = (unsigned)iy1 < (unsigned)HH;
                float v00 = (vx0 && vy0) ? bf2f(xb[(size_t)((iy0 << 7) + ix0) * CH + lane]) : 0.0f;
                float v10 = (vx1 && vy0) ? bf2f(xb[(size_t)((iy0 << 7) + ix1) * CH + lane]) : 0.0f;
                float v01 = (vx0 && vy1) ? bf2f(xb[(size_t)((iy1 << 7) + ix0) * CH + lane]) : 0.0f;
                float v11 = (vx1 && vy1) ? bf2f(xb[(size_t)((iy1 << 7) + ix1) * CH + lane]) : 0.0f;
                float s = (v00 * wx0 + v10 * wx1) * wy0 + (v01 * wx0 + v11 * wx1) * wy1;
                s_w[p * ROW_BF + tl * 64 + lane] = f2bf(s);
            }
        }
        // ---- MFMA over this chunk: 6 k-steps x 4 n-tiles ----
        // (wave-private LDS: no barrier; compiler inserts lgkmcnt waits)
#pragma unroll
        for (int ksl = 0; ksl < 6; ++ksl) {
            int ks = ch * 6 + ksl;
            short8 a = *(const short8*)(s_w + m * ROW_BF + ksl * 32 + quad * 8);
#pragma unroll
            for (int nt = 0; nt < 4; ++nt) {
                short8 b = bfrags[(ks * 4 + nt) * 64 + lane];
                acc[nt] = __builtin_amdgcn_mfma_f32_16x16x32_bf16(a, b, acc[nt], 0, 0, 0);
            }
        }
    }

    // ---- epilogue: acc -> wave-private LDS (reuse A-tile space) ----
    float* o_w = (float*)(smem + wave * WAVE_BYTES);
#pragma unroll
    for (int nt = 0; nt < 4; ++nt)
#pragma unroll
        for (int reg = 0; reg < 4; ++reg)
            o_w[(quad * 4 + reg) * 65 + nt * 16 + m] = acc[nt][reg];
    __syncthreads();

    // ---- block-wide coalesced store: 64 consecutive pixels per o-row ----
    int Pb0 = blockIdx.x * 64;
    int b = Pb0 >> 14;
    int rem0 = Pb0 & (HW - 1);
#pragma unroll
    for (int j = tid; j < 64 * 64; j += 256) {
        int o = j >> 6;
        int p = j & 63;
        int w2 = p >> 4, mm = p & 15;
        float v = ((const float*)(smem + w2 * WAVE_BYTES))[mm * 65 + o] + bias[o];
        out[(((size_t)(b * OH + o)) << 14) + rem0 + p] = v;
    }
}

extern "C" void kernel_launch(void* const* d_in, const int* in_sizes, int n_in,
                              void* d_out, int out_size, void* d_ws, size_t ws_size,
                              hipStream_t stream) {
    const float* x      = (const float*)d_in[0];
    const float* offset = (const float*)d_in[1];
    const float* weight = (const float*)d_in[2];
    const float* bias   = (const float*)d_in[3];
    float* out = (float*)d_out;

    unsigned short* xt  = (unsigned short*)d_ws;                       // 8.39 MB
    unsigned short* wtb = (unsigned short*)((char*)d_ws + (size_t)BH * HW * CH * 2);

    dcl_transpose<<<(BH * HW) / 64, dim3(64, 4), 0, stream>>>(x, xt);
    dcl_wpack<<<(18 * 4 * 64 * 8) / 256, 256, 0, stream>>>(weight, wtb);
    dcl_main<<<(BH * HW) / 64, 256, 0, stream>>>(xt, offset, wtb, bias, out);
}

// Round 3
// 121.800 us; speedup vs baseline: 2.2415x; 2.2415x over previous
//
#include <hip/hip_runtime.h>
#include <cstddef>

#define BH 4
#define CH 64
#define OH 64
#define HH 128
#define WW 128
#define KK 9
#define HW (HH * WW)     // 16384

typedef __attribute__((ext_vector_type(8))) short short8;       // 8 bf16
typedef __attribute__((ext_vector_type(4))) float f32x4;        // MFMA acc
typedef __attribute__((ext_vector_type(2))) float f32x2;
typedef __attribute__((ext_vector_type(4))) unsigned int uint4v;

__device__ __forceinline__ unsigned short f2bf(float f) {
    unsigned u = __float_as_uint(f);
    u += 0x7fffu + ((u >> 16) & 1u);   // round-to-nearest-even
    return (unsigned short)(u >> 16);
}

// unpack dword (2 bf16) -> 2 f32
__device__ __forceinline__ f32x2 bf2x2(unsigned d) {
    f32x2 r;
    r.x = __uint_as_float(d << 16);
    r.y = __uint_as_float(d & 0xffff0000u);
    return r;
}
// RNE-round 2 f32 -> packed 2 bf16 (elem0 in low16)
__device__ __forceinline__ unsigned pack_bf2(f32x2 v) {
    unsigned u0 = __float_as_uint(v.x);
    u0 += 0x7fffu + ((u0 >> 16) & 1u);
    unsigned u1 = __float_as_uint(v.y);
    u1 += 0x7fffu + ((u1 >> 16) & 1u);
    return __builtin_amdgcn_perm(u1, u0, 0x07060302);
}

// bilinear combine of 4 corner uint4 (8 bf16 each) with 4 weights -> packed bf16 uint4
__device__ __forceinline__ uint4v combine4(uint4v c00, uint4v c10, uint4v c01, uint4v c11,
                                           float w00, float w10, float w01, float w11) {
    f32x2 W00 = {w00, w00}, W10 = {w10, w10}, W01 = {w01, w01}, W11 = {w11, w11};
    uint4v r;
#pragma unroll
    for (int j = 0; j < 4; ++j) {
        f32x2 s = W00 * bf2x2(c00[j]) + W10 * bf2x2(c10[j])
                + W01 * bf2x2(c01[j]) + W11 * bf2x2(c11[j]);
        r[j] = pack_bf2(s);
    }
    return r;
}

// ---------------------------------------------------------------------------
// Transpose x[b][c][h][w] f32 -> xt[b][h][w][c] bf16
// ---------------------------------------------------------------------------
__global__ __launch_bounds__(256) void dcl_transpose(const float* __restrict__ x,
                                                     unsigned short* __restrict__ xt) {
    __shared__ float tile[64][65];
    int chunk = blockIdx.x;              // 0 .. 1023
    int b = chunk >> 8;
    int hw0 = (chunk & 255) * 64;
    int tx = threadIdx.x;                // 0..63
    int ty = threadIdx.y;                // 0..3
    const float* xb = x + (size_t)b * CH * HW;
    for (int c = ty; c < 64; c += 4)
        tile[c][tx] = xb[(size_t)c * HW + hw0 + tx];
    __syncthreads();
    unsigned short* xtb = xt + ((size_t)b << 20);
    for (int i = ty; i < 64; i += 4)
        xtb[(size_t)(hw0 + i) * CH + tx] = f2bf(tile[tx][i]);
}

// ---------------------------------------------------------------------------
// Pack weight[o][c][t] f32 -> B fragments for mfma_f32_16x16x32_bf16.
// lane l of frag (ks,nt) holds B[k][n], k=ks*32+(l>>4)*8+j, n=nt*16+(l&15),
// with k = t*64 + c.   addr: wtb[((ks*4+nt)*64 + l)*8 + j]
// ---------------------------------------------------------------------------
__global__ __launch_bounds__(256) void dcl_wpack(const float* __restrict__ wgt,
                                                 unsigned short* __restrict__ wtb) {
    int idx = blockIdx.x * 256 + threadIdx.x;   // 0 .. 36863
    int j  = idx & 7;
    int l  = (idx >> 3) & 63;
    int nt = (idx >> 9) & 3;
    int ks = idx >> 11;
    int k = ks * 32 + ((l >> 4) * 8) + j;
    int n = nt * 16 + (l & 15);
    int c = k & 63;
    int t = k >> 6;
    wtb[idx] = f2bf(wgt[(n * CH + c) * KK + t]);
}

// ---------------------------------------------------------------------------
// Main kernel: block = 4 waves, wave = 16 pixels.
// Phase A: lanes compute per-(pixel,tap) prep (4 clamped byte-offsets into xt,
//          4 validity-masked bilinear weights) -> wave-private LDS.
// Phase B: per tap, lane (m,quad) gathers pixel m channels quad*8..+7 for the
//          4 corners (8x dwordx4), combines in-register, packs bf16 A-frags,
//          runs 2 k-steps x 4 n-tiles of MFMA. No sample LDS roundtrip.
// ---------------------------------------------------------------------------
#define WAVE_WORDS 1200   // per-wave LDS: prep 9*8*16=1152 words; epilogue 16*65=1040

__global__ __launch_bounds__(256, 4) void dcl_main(
        const unsigned short* __restrict__ xt,   // [b][h][w][c] bf16
        const float* __restrict__ offset,
        const unsigned short* __restrict__ wtb,  // packed B fragments
        const float* __restrict__ bias,
        float* __restrict__ out) {
    __shared__ int smem[4 * WAVE_WORDS];
    int tid = threadIdx.x;
    int lane = tid & 63;
    int wave = tid >> 6;
    int* s_w = smem + wave * WAVE_WORDS;

    int P0 = blockIdx.x * 64 + wave * 16;
    int b = P0 >> 14;
    int rem0 = P0 & (HW - 1);
    int y = rem0 >> 7;          // same row for the whole block (64 | HW rows)
    int x0 = rem0 & 127;
    int m = lane & 15;
    int quad = lane >> 4;

    // ---- Phase A: prep 16 px x 9 taps across lanes ----
    {
        int pm = lane & 15;
        int q = lane >> 4;
        float fx_base = (float)(x0 + pm);
        const float* offbase = offset + (((size_t)(b * 18)) << 14) + (rem0 + pm);
#pragma unroll
        for (int r = 0; r < 3; ++r) {
            int t = r * 4 + q;
            if (t < 9) {
                float ox = offbase[(size_t)(2 * t) << 14];
                float oy = offbase[(size_t)(2 * t + 1) << 14];
                float fx = fx_base + ox;
                float fy = (float)y + oy;
                float x0f = floorf(fx), y0f = floorf(fy);
                float wx1 = fx - x0f, wy1 = fy - y0f;
                float wx0 = 1.0f - wx1, wy0 = 1.0f - wy1;
                int ix0 = (int)x0f, iy0 = (int)y0f;
                int ix1 = ix0 + 1, iy1 = iy0 + 1;
                bool vx0 = (unsigned)ix0 < (unsigned)WW;
                bool vx1 = (unsigned)ix1 < (unsigned)WW;
                bool vy0 = (unsigned)iy0 < (unsigned)HH;
                bool vy1 = (unsigned)iy1 < (unsigned)HH;
                float w00 = (vx0 && vy0) ? wx0 * wy0 : 0.0f;
                float w10 = (vx1 && vy0) ? wx1 * wy0 : 0.0f;
                float w01 = (vx0 && vy1) ? wx0 * wy1 : 0.0f;
                float w11 = (vx1 && vy1) ? wx1 * wy1 : 0.0f;
                int cx0 = min(max(ix0, 0), WW - 1), cx1 = min(max(ix1, 0), WW - 1);
                int cy0 = min(max(iy0, 0), HH - 1), cy1 = min(max(iy1, 0), HH - 1);
                int base = b << 14;
                int o00 = (base + (cy0 << 7) + cx0) << 7;   // byte offset (128 B/px)
                int o10 = (base + (cy0 << 7) + cx1) << 7;
                int o01 = (base + (cy1 << 7) + cx0) << 7;
                int o11 = (base + (cy1 << 7) + cx1) << 7;
                int* pp = s_w + t * 128 + pm;   // field-major: [t][field][16]
                pp[0]   = __float_as_int(w00);
                pp[16]  = __float_as_int(w10);
                pp[32]  = __float_as_int(w01);
                pp[48]  = __float_as_int(w11);
                pp[64]  = o00;
                pp[80]  = o10;
                pp[96]  = o01;
                pp[112] = o11;
            }
        }
    }
    // wave-private LDS: no barrier needed (compiler inserts lgkmcnt waits)

    f32x4 acc[4];
#pragma unroll
    for (int i = 0; i < 4; ++i) acc[i] = (f32x4)(0.f);

    const short8* bfrags = (const short8*)wtb;
    const char* xtb = (const char*)xt;

    // ---- Phase B: 9 taps, fully unrolled for ILP ----
#pragma unroll
    for (int t = 0; t < 9; ++t) {
        const int* pp = s_w + t * 128 + m;
        float w00 = __int_as_float(pp[0]);
        float w10 = __int_as_float(pp[16]);
        float w01 = __int_as_float(pp[32]);
        float w11 = __int_as_float(pp[48]);
        int qoff = quad * 16;
        int o00 = pp[64]  + qoff;
        int o10 = pp[80]  + qoff;
        int o01 = pp[96]  + qoff;
        int o11 = pp[112] + qoff;
        // 8 independent 16B gathers: 4 corners x 2 k-steps (channels 0-31 / 32-63)
        uint4v c00a = *(const uint4v*)(xtb + o00);
        uint4v c10a = *(const uint4v*)(xtb + o10);
        uint4v c01a = *(const uint4v*)(xtb + o01);
        uint4v c11a = *(const uint4v*)(xtb + o11);
        uint4v c00b = *(const uint4v*)(xtb + o00 + 64);
        uint4v c10b = *(const uint4v*)(xtb + o10 + 64);
        uint4v c01b = *(const uint4v*)(xtb + o01 + 64);
        uint4v c11b = *(const uint4v*)(xtb + o11 + 64);
        uint4v ra = combine4(c00a, c10a, c01a, c11a, w00, w10, w01, w11);
        uint4v rb = combine4(c00b, c10b, c01b, c11b, w00, w10, w01, w11);
        short8 aa = __builtin_bit_cast(short8, ra);
        short8 ab = __builtin_bit_cast(short8, rb);
        int ks = 2 * t;
#pragma unroll
        for (int nt = 0; nt < 4; ++nt)
            acc[nt] = __builtin_amdgcn_mfma_f32_16x16x32_bf16(
                aa, bfrags[(ks * 4 + nt) * 64 + lane], acc[nt], 0, 0, 0);
#pragma unroll
        for (int nt = 0; nt < 4; ++nt)
            acc[nt] = __builtin_amdgcn_mfma_f32_16x16x32_bf16(
                ab, bfrags[((ks + 1) * 4 + nt) * 64 + lane], acc[nt], 0, 0, 0);
    }

    // ---- Epilogue: acc -> wave-private LDS (reuse prep area) ----
    float* o_w = (float*)s_w;
#pragma unroll
    for (int nt = 0; nt < 4; ++nt)
#pragma unroll
        for (int reg = 0; reg < 4; ++reg)
            o_w[(quad * 4 + reg) * 65 + nt * 16 + m] = acc[nt][reg];
    __syncthreads();

    // ---- Block-wide coalesced store: 64 consecutive pixels per o-row ----
    int Pb0 = blockIdx.x * 64;
    int remb = Pb0 & (HW - 1);
#pragma unroll
    for (int j = tid; j < 64 * 64; j += 256) {
        int o = j >> 6;            // wave-uniform per iteration
        int p = j & 63;
        int w2 = p >> 4, mm = p & 15;
        float v = ((const float*)(smem + w2 * WAVE_WORDS))[mm * 65 + o] + bias[o];
        out[(((size_t)(b * OH + o)) << 14) + remb + p] = v;
    }
}

extern "C" void kernel_launch(void* const* d_in, const int* in_sizes, int n_in,
                              void* d_out, int out_size, void* d_ws, size_t ws_size,
                              hipStream_t stream) {
    const float* x      = (const float*)d_in[0];
    const float* offset = (const float*)d_in[1];
    const float* weight = (const float*)d_in[2];
    const float* bias   = (const float*)d_in[3];
    float* out = (float*)d_out;

    unsigned short* xt  = (unsigned short*)d_ws;                       // 8.39 MB
    unsigned short* wtb = (unsigned short*)((char*)d_ws + (size_t)BH * HW * CH * 2);

    dcl_transpose<<<(BH * HW) / 64, dim3(64, 4), 0, stream>>>(x, xt);
    dcl_wpack<<<(18 * 4 * 64 * 8) / 256, 256, 0, stream>>>(weight, wtb);
    dcl_main<<<(BH * HW) / 64, 256, 0, stream>>>(xt, offset, wtb, bias, out);
}

// Round 4
// 119.218 us; speedup vs baseline: 2.2900x; 1.0217x over previous
//
#include <hip/hip_runtime.h>
#include <cstddef>

#define BH 4
#define CH 64
#define OH 64
#define HH 128
#define WW 128
#define KK 9
#define HW (HH * WW)     // 16384

typedef __attribute__((ext_vector_type(8))) short short8;       // 8 bf16
typedef __attribute__((ext_vector_type(4))) float f32x4;        // MFMA acc
typedef __attribute__((ext_vector_type(2))) float f32x2;
typedef __attribute__((ext_vector_type(4))) unsigned int uint4v;
typedef __attribute__((ext_vector_type(4))) unsigned short ushort4v;

__device__ __forceinline__ unsigned short f2bf(float f) {
    unsigned u = __float_as_uint(f);
    u += 0x7fffu + ((u >> 16) & 1u);   // RNE
    return (unsigned short)(u >> 16);
}
__device__ __forceinline__ f32x2 bf2x2(unsigned d) {
    f32x2 r;
    r.x = __uint_as_float(d << 16);
    r.y = __uint_as_float(d & 0xffff0000u);
    return r;
}
__device__ __forceinline__ unsigned pack_bf2(f32x2 v) {
    unsigned u0 = __float_as_uint(v.x);
    u0 += 0x7fffu + ((u0 >> 16) & 1u);
    unsigned u1 = __float_as_uint(v.y);
    u1 += 0x7fffu + ((u1 >> 16) & 1u);
    return __builtin_amdgcn_perm(u1, u0, 0x07060302);
}
__device__ __forceinline__ uint4v combine4(uint4v c00, uint4v c10, uint4v c01, uint4v c11,
                                           float w00, float w10, float w01, float w11) {
    f32x2 W00 = {w00, w00}, W10 = {w10, w10}, W01 = {w01, w01}, W11 = {w11, w11};
    uint4v r;
#pragma unroll
    for (int j = 0; j < 4; ++j) {
        f32x2 s = W00 * bf2x2(c00[j]) + W10 * bf2x2(c10[j])
                + W01 * bf2x2(c01[j]) + W11 * bf2x2(c11[j]);
        r[j] = pack_bf2(s);
    }
    return r;
}

// ---------------------------------------------------------------------------
// Fused prep: blocks 0..1023 transpose x NCHW f32 -> NHWC bf16;
// blocks 1024..1167 pack weight into MFMA B fragments.
// ---------------------------------------------------------------------------
__global__ __launch_bounds__(256) void dcl_prep(const float* __restrict__ x,
                                                const float* __restrict__ wgt,
                                                unsigned short* __restrict__ xt,
                                                unsigned short* __restrict__ wtb) {
    if (blockIdx.x < 1024) {
        __shared__ float tile[64][65];
        int chunk = blockIdx.x;
        int b = chunk >> 8;
        int hw0 = (chunk & 255) * 64;
        int tid = threadIdx.x;          // 0..255
        int tx = tid & 63;
        int ty = tid >> 6;
        const float* xb = x + (size_t)b * CH * HW;
#pragma unroll
        for (int c = ty; c < 64; c += 4)
            tile[c][tx] = xb[(size_t)c * HW + hw0 + tx];
        __syncthreads();
        unsigned short* xtb = xt + ((size_t)b << 20);
        int c4 = (tid & 15) * 4;
        int p0 = tid >> 4;              // 0..15
#pragma unroll
        for (int it = 0; it < 4; ++it) {
            int pxl = p0 + it * 16;
            ushort4v v = { f2bf(tile[c4 + 0][pxl]), f2bf(tile[c4 + 1][pxl]),
                           f2bf(tile[c4 + 2][pxl]), f2bf(tile[c4 + 3][pxl]) };
            *(ushort4v*)(xtb + (size_t)(hw0 + pxl) * CH + c4) = v;
        }
    } else {
        // wpack: lane l of frag (ks,nt) holds B[k][n], k=ks*32+(l>>4)*8+j,
        // n=nt*16+(l&15), k=t*64+c.  addr: wtb[((ks*4+nt)*64+l)*8+j]
        int idx = (blockIdx.x - 1024) * 256 + threadIdx.x;   // 0..36863
        int j  = idx & 7;
        int l  = (idx >> 3) & 63;
        int nt = (idx >> 9) & 3;
        int ks = idx >> 11;
        int k = ks * 32 + ((l >> 4) * 8) + j;
        int n = nt * 16 + (l & 15);
        int c = k & 63;
        int t = k >> 6;
        wtb[idx] = f2bf(wgt[(n * CH + c) * KK + t]);
    }
}

// ---------------------------------------------------------------------------
// Main: block = 2 waves sharing 16 pixels (K-split: wave0 taps 0-4,
// wave1 taps 5-8), grid 4096 -> 8192 waves (2x occupancy vs R3).
// Phase A: 128 threads prep all 144 (p,t) pairs -> block LDS.
// Phase B: per tap: 8x dwordx4 corner gathers in A-frag layout, in-register
// bilinear combine, bf16 pack, 2 k-steps x 4 n-tiles MFMA.
// Epilogue: both waves' partial C summed via LDS, coalesced store.
// ---------------------------------------------------------------------------
#define PREP_WORDS 1152            // 9 taps * 8 fields * 16 px
#define OAREA_WORDS 1040           // 16 * 65
#define SMEM_WORDS (2 * OAREA_WORDS)   // 2080 > 1152 (epilogue reuses prep)

__global__ __launch_bounds__(128, 8) void dcl_main(
        const unsigned short* __restrict__ xt,   // [b][h][w][c] bf16
        const float* __restrict__ offset,
        const unsigned short* __restrict__ wtb,  // packed B fragments
        const float* __restrict__ bias,
        float* __restrict__ out) {
    __shared__ int smem[SMEM_WORDS];
    int tid = threadIdx.x;          // 0..127
    int lane = tid & 63;
    int wave = tid >> 6;            // 0..1

    int P0 = blockIdx.x * 16;
    int b = P0 >> 14;
    int rem0 = P0 & (HW - 1);
    int y = rem0 >> 7;
    int x0 = rem0 & 127;
    int m = lane & 15;
    int quad = lane >> 4;

    // ---- Phase A: prep (pixel pm, tap t) -> weights + clamped byte offsets ----
    {
#pragma unroll
        for (int rr = 0; rr < 2; ++rr) {
            int e = tid + rr * 128;
            if (e < 144) {
                int t = e >> 4;
                int pm = e & 15;
                const float* offbase = offset + (((size_t)(b * 18)) << 14) + (rem0 + pm);
                float ox = offbase[(size_t)(2 * t) << 14];
                float oy = offbase[(size_t)(2 * t + 1) << 14];
                float fx = (float)(x0 + pm) + ox;
                float fy = (float)y + oy;
                float x0f = floorf(fx), y0f = floorf(fy);
                float wx1 = fx - x0f, wy1 = fy - y0f;
                float wx0 = 1.0f - wx1, wy0 = 1.0f - wy1;
                int ix0 = (int)x0f, iy0 = (int)y0f;
                int ix1 = ix0 + 1, iy1 = iy0 + 1;
                bool vx0 = (unsigned)ix0 < (unsigned)WW;
                bool vx1 = (unsigned)ix1 < (unsigned)WW;
                bool vy0 = (unsigned)iy0 < (unsigned)HH;
                bool vy1 = (unsigned)iy1 < (unsigned)HH;
                float w00 = (vx0 && vy0) ? wx0 * wy0 : 0.0f;
                float w10 = (vx1 && vy0) ? wx1 * wy0 : 0.0f;
                float w01 = (vx0 && vy1) ? wx0 * wy1 : 0.0f;
                float w11 = (vx1 && vy1) ? wx1 * wy1 : 0.0f;
                int cx0 = min(max(ix0, 0), WW - 1), cx1 = min(max(ix1, 0), WW - 1);
                int cy0 = min(max(iy0, 0), HH - 1), cy1 = min(max(iy1, 0), HH - 1);
                int base = b << 14;
                int o00 = (base + (cy0 << 7) + cx0) << 7;   // byte offsets (128 B/px)
                int o10 = (base + (cy0 << 7) + cx1) << 7;
                int o01 = (base + (cy1 << 7) + cx0) << 7;
                int o11 = (base + (cy1 << 7) + cx1) << 7;
                int* pp = smem + t * 128 + pm;              // [t][field][16]
                pp[0]   = __float_as_int(w00);
                pp[16]  = __float_as_int(w10);
                pp[32]  = __float_as_int(w01);
                pp[48]  = __float_as_int(w11);
                pp[64]  = o00;
                pp[80]  = o10;
                pp[96]  = o01;
                pp[112] = o11;
            }
        }
    }
    __syncthreads();

    f32x4 acc[4];
#pragma unroll
    for (int i = 0; i < 4; ++i) acc[i] = (f32x4)(0.f);

    const short8* bfrags = (const short8*)wtb;
    const char* xtb = (const char*)xt;

    // ---- Phase B: wave0 -> taps 0..4, wave1 -> taps 5..8 ----
    int tbase = wave ? 5 : 0;
    int tcnt  = wave ? 4 : 5;
#pragma unroll
    for (int i = 0; i < 5; ++i) {
        if (i < tcnt) {                       // wave-uniform branch
            int t = tbase + i;
            const int* pp = smem + t * 128 + m;
            float w00 = __int_as_float(pp[0]);
            float w10 = __int_as_float(pp[16]);
            float w01 = __int_as_float(pp[32]);
            float w11 = __int_as_float(pp[48]);
            int qoff = quad * 16;
            int o00 = pp[64]  + qoff;
            int o10 = pp[80]  + qoff;
            int o01 = pp[96]  + qoff;
            int o11 = pp[112] + qoff;
            uint4v c00a = *(const uint4v*)(xtb + o00);
            uint4v c10a = *(const uint4v*)(xtb + o10);
            uint4v c01a = *(const uint4v*)(xtb + o01);
            uint4v c11a = *(const uint4v*)(xtb + o11);
            uint4v c00b = *(const uint4v*)(xtb + o00 + 64);
            uint4v c10b = *(const uint4v*)(xtb + o10 + 64);
            uint4v c01b = *(const uint4v*)(xtb + o01 + 64);
            uint4v c11b = *(const uint4v*)(xtb + o11 + 64);
            uint4v ra = combine4(c00a, c10a, c01a, c11a, w00, w10, w01, w11);
            uint4v rb = combine4(c00b, c10b, c01b, c11b, w00, w10, w01, w11);
            short8 aa = __builtin_bit_cast(short8, ra);
            short8 ab = __builtin_bit_cast(short8, rb);
            int ks = 2 * t;
#pragma unroll
            for (int nt = 0; nt < 4; ++nt)
                acc[nt] = __builtin_amdgcn_mfma_f32_16x16x32_bf16(
                    aa, bfrags[(ks * 4 + nt) * 64 + lane], acc[nt], 0, 0, 0);
#pragma unroll
            for (int nt = 0; nt < 4; ++nt)
                acc[nt] = __builtin_amdgcn_mfma_f32_16x16x32_bf16(
                    ab, bfrags[((ks + 1) * 4 + nt) * 64 + lane], acc[nt], 0, 0, 0);
        }
    }

    // ---- Epilogue: per-wave partial C -> LDS, then sum + store ----
    __syncthreads();   // prep area is about to be overwritten
    float* o_w = (float*)(smem + wave * OAREA_WORDS);
#pragma unroll
    for (int nt = 0; nt < 4; ++nt)
#pragma unroll
        for (int reg = 0; reg < 4; ++reg)
            o_w[(quad * 4 + reg) * 65 + nt * 16 + m] = acc[nt][reg];   // [px][out]
    __syncthreads();

    const float* o0 = (const float*)smem;
    const float* o1 = (const float*)(smem + OAREA_WORDS);
#pragma unroll
    for (int j = tid; j < 16 * 64; j += 128) {
        int o = j >> 4;          // wave-uniform per iteration
        int p = j & 15;
        float v = o0[p * 65 + o] + o1[p * 65 + o] + bias[o];
        out[(((size_t)(b * OH + o)) << 14) + rem0 + p] = v;
    }
}

extern "C" void kernel_launch(void* const* d_in, const int* in_sizes, int n_in,
                              void* d_out, int out_size, void* d_ws, size_t ws_size,
                              hipStream_t stream) {
    const float* x      = (const float*)d_in[0];
    const float* offset = (const float*)d_in[1];
    const float* weight = (const float*)d_in[2];
    const float* bias   = (const float*)d_in[3];
    float* out = (float*)d_out;

    unsigned short* xt  = (unsigned short*)d_ws;                           // 8.39 MB
    unsigned short* wtb = (unsigned short*)((char*)d_ws + (size_t)BH * HW * CH * 2);

    dcl_prep<<<1024 + 144, 256, 0, stream>>>(x, weight, xt, wtb);
    dcl_main<<<(BH * HW) / 16, 128, 0, stream>>>(xt, offset, wtb, bias, out);
}

// Round 5
// 113.213 us; speedup vs baseline: 2.4115x; 1.0530x over previous
//
#include <hip/hip_runtime.h>
#include <cstddef>

#define BH 4
#define CH 64
#define OH 64
#define HH 128
#define WW 128
#define KK 9
#define HW (HH * WW)     // 16384

typedef __attribute__((ext_vector_type(8))) short short8;       // 8 bf16
typedef __attribute__((ext_vector_type(4))) float f32x4;        // MFMA acc
typedef __attribute__((ext_vector_type(2))) float f32x2;
typedef __attribute__((ext_vector_type(4))) unsigned int uint4v;
typedef __attribute__((ext_vector_type(4))) unsigned short ushort4v;

__device__ __forceinline__ unsigned short f2bf(float f) {
    unsigned u = __float_as_uint(f);
    u += 0x7fffu + ((u >> 16) & 1u);   // RNE
    return (unsigned short)(u >> 16);
}
__device__ __forceinline__ f32x2 bf2x2(unsigned d) {
    f32x2 r;
    r.x = __uint_as_float(d << 16);
    r.y = __uint_as_float(d & 0xffff0000u);
    return r;
}
__device__ __forceinline__ unsigned pack_bf2(f32x2 v) {
    unsigned u0 = __float_as_uint(v.x);
    u0 += 0x7fffu + ((u0 >> 16) & 1u);
    unsigned u1 = __float_as_uint(v.y);
    u1 += 0x7fffu + ((u1 >> 16) & 1u);
    return __builtin_amdgcn_perm(u1, u0, 0x07060302);
}
__device__ __forceinline__ uint4v combine4(uint4v c00, uint4v c10, uint4v c01, uint4v c11,
                                           float w00, float w10, float w01, float w11) {
    f32x2 W00 = {w00, w00}, W10 = {w10, w10}, W01 = {w01, w01}, W11 = {w11, w11};
    uint4v r;
#pragma unroll
    for (int j = 0; j < 4; ++j) {
        f32x2 s = W00 * bf2x2(c00[j]) + W10 * bf2x2(c10[j])
                + W01 * bf2x2(c01[j]) + W11 * bf2x2(c11[j]);
        r[j] = pack_bf2(s);
    }
    return r;
}

// ---------------------------------------------------------------------------
// Fused prep: blocks 0..1023 transpose x NCHW f32 -> NHWC bf16;
// blocks 1024..1167 pack weight into MFMA B fragments.
// ---------------------------------------------------------------------------
__global__ __launch_bounds__(256) void dcl_prep(const float* __restrict__ x,
                                                const float* __restrict__ wgt,
                                                unsigned short* __restrict__ xt,
                                                unsigned short* __restrict__ wtb) {
    if (blockIdx.x < 1024) {
        __shared__ float tile[64][65];
        int chunk = blockIdx.x;
        int b = chunk >> 8;
        int hw0 = (chunk & 255) * 64;
        int tid = threadIdx.x;          // 0..255
        int tx = tid & 63;
        int ty = tid >> 6;
        const float* xb = x + (size_t)b * CH * HW;
#pragma unroll
        for (int c = ty; c < 64; c += 4)
            tile[c][tx] = xb[(size_t)c * HW + hw0 + tx];
        __syncthreads();
        unsigned short* xtb = xt + ((size_t)b << 20);
        int c4 = (tid & 15) * 4;
        int p0 = tid >> 4;              // 0..15
#pragma unroll
        for (int it = 0; it < 4; ++it) {
            int pxl = p0 + it * 16;
            ushort4v v = { f2bf(tile[c4 + 0][pxl]), f2bf(tile[c4 + 1][pxl]),
                           f2bf(tile[c4 + 2][pxl]), f2bf(tile[c4 + 3][pxl]) };
            *(ushort4v*)(xtb + (size_t)(hw0 + pxl) * CH + c4) = v;
        }
    } else {
        // wpack: lane l of frag (ks,nt) holds B[k][n], k=ks*32+(l>>4)*8+j,
        // n=nt*16+(l&15), k=t*64+c.  addr: wtb[((ks*4+nt)*64+l)*8+j]
        int idx = (blockIdx.x - 1024) * 256 + threadIdx.x;   // 0..36863
        int j  = idx & 7;
        int l  = (idx >> 3) & 63;
        int nt = (idx >> 9) & 3;
        int ks = idx >> 11;
        int k = ks * 32 + ((l >> 4) * 8) + j;
        int n = nt * 16 + (l & 15);
        int c = k & 63;
        int t = k >> 6;
        wtb[idx] = f2bf(wgt[(n * CH + c) * KK + t]);
    }
}

// ---------------------------------------------------------------------------
// Main: block = 8 waves = 128 px (one full image row). Each wave owns 16 px,
// all 9 taps. B fragments staged to LDS in 3 chunks of 3 taps (24 KB),
// amortized across all 8 waves; B reads leave the vmcnt path (ds_read_b128).
// Prep (bilinear weights + clamped corner offsets) computed per-lane in
// registers (4x redundant across quads; offset loads are 1-line coalesced).
// ---------------------------------------------------------------------------
#define NW 8
#define CHUNK_BYTES 24576            // 3 taps * 2 ks * 4 nt * 1 KB
#define OSLICE_WORDS 1040            // 16 * 65
#define SMEM_WORDS (NW * OSLICE_WORDS)   // 8320 words = 33280 B (> 24 KB chunk)

__global__ __launch_bounds__(512, 4) void dcl_main(
        const unsigned short* __restrict__ xt,   // [b][h][w][c] bf16
        const float* __restrict__ offset,
        const unsigned short* __restrict__ wtb,  // packed B fragments (72 KB)
        const float* __restrict__ bias,
        float* __restrict__ out) {
    __shared__ int smem[SMEM_WORDS];
    int tid = threadIdx.x;          // 0..511
    int lane = tid & 63;
    int wave = tid >> 6;            // 0..7

    int row = blockIdx.x;           // 0..511 : one full image row per block
    int b = row >> 7;
    int y = row & 127;
    int m = lane & 15;
    int quad = lane >> 4;
    int qoff = quad * 16;
    int pm = wave * 16 + m;         // pixel x-coordinate (0..127)

    const char* xtb = (const char*)xt;
    const float* ob = offset + (((size_t)(b * 18)) << 14) + (y << 7) + pm;
    float pxf = (float)pm;
    float pyf = (float)y;

    f32x4 acc[4];
#pragma unroll
    for (int i = 0; i < 4; ++i) acc[i] = (f32x4)(0.f);

    const short8* bl = (const short8*)smem;

#pragma unroll
    for (int c = 0; c < 3; ++c) {
        // ---- stage B chunk (3 taps, 24 KB) to LDS ----
        if (c) __syncthreads();                 // prev chunk fully consumed
        {
            const uint4v* bsrc = (const uint4v*)((const char*)wtb + c * CHUNK_BYTES);
            uint4v* bdst = (uint4v*)smem;
#pragma unroll
            for (int r = 0; r < 3; ++r)
                bdst[r * 512 + tid] = bsrc[r * 512 + tid];
        }
        // ---- per-chunk offset preload (1-line coalesced loads) ----
        float oxv[3], oyv[3];
#pragma unroll
        for (int tl = 0; tl < 3; ++tl) {
            int t = c * 3 + tl;
            oxv[tl] = ob[(size_t)(2 * t) << 14];
            oyv[tl] = ob[(size_t)(2 * t + 1) << 14];
        }
        __syncthreads();                        // B chunk visible

        // ---- 3 taps ----
#pragma unroll
        for (int tl = 0; tl < 3; ++tl) {
            float fx = pxf + oxv[tl];
            float fy = pyf + oyv[tl];
            float x0f = floorf(fx), y0f = floorf(fy);
            float wx1 = fx - x0f, wy1 = fy - y0f;
            float wx0 = 1.0f - wx1, wy0 = 1.0f - wy1;
            int ix0 = (int)x0f, iy0 = (int)y0f;
            int ix1 = ix0 + 1, iy1 = iy0 + 1;
            bool vx0 = (unsigned)ix0 < (unsigned)WW;
            bool vx1 = (unsigned)ix1 < (unsigned)WW;
            bool vy0 = (unsigned)iy0 < (unsigned)HH;
            bool vy1 = (unsigned)iy1 < (unsigned)HH;
            float w00 = (vx0 && vy0) ? wx0 * wy0 : 0.0f;
            float w10 = (vx1 && vy0) ? wx1 * wy0 : 0.0f;
            float w01 = (vx0 && vy1) ? wx0 * wy1 : 0.0f;
            float w11 = (vx1 && vy1) ? wx1 * wy1 : 0.0f;
            int cx0 = min(max(ix0, 0), WW - 1), cx1 = min(max(ix1, 0), WW - 1);
            int cy0 = min(max(iy0, 0), HH - 1), cy1 = min(max(iy1, 0), HH - 1);
            int base = b << 14;
            int o00 = ((base + (cy0 << 7) + cx0) << 7) + qoff;   // 128 B per px
            int o10 = ((base + (cy0 << 7) + cx1) << 7) + qoff;
            int o01 = ((base + (cy1 << 7) + cx0) << 7) + qoff;
            int o11 = ((base + (cy1 << 7) + cx1) << 7) + qoff;

            uint4v c00a = *(const uint4v*)(xtb + o00);
            uint4v c10a = *(const uint4v*)(xtb + o10);
            uint4v c01a = *(const uint4v*)(xtb + o01);
            uint4v c11a = *(const uint4v*)(xtb + o11);
            uint4v c00b = *(const uint4v*)(xtb + o00 + 64);
            uint4v c10b = *(const uint4v*)(xtb + o10 + 64);
            uint4v c01b = *(const uint4v*)(xtb + o01 + 64);
            uint4v c11b = *(const uint4v*)(xtb + o11 + 64);
            uint4v ra = combine4(c00a, c10a, c01a, c11a, w00, w10, w01, w11);
            uint4v rb = combine4(c00b, c10b, c01b, c11b, w00, w10, w01, w11);
            short8 aa = __builtin_bit_cast(short8, ra);
            short8 ab = __builtin_bit_cast(short8, rb);

            int f0 = (tl * 2) * 4;              // chunk-local fragment index
#pragma unroll
            for (int nt = 0; nt < 4; ++nt)
                acc[nt] = __builtin_amdgcn_mfma_f32_16x16x32_bf16(
                    aa, bl[(f0 + nt) * 64 + lane], acc[nt], 0, 0, 0);
#pragma unroll
            for (int nt = 0; nt < 4; ++nt)
                acc[nt] = __builtin_amdgcn_mfma_f32_16x16x32_bf16(
                    ab, bl[(f0 + 4 + nt) * 64 + lane], acc[nt], 0, 0, 0);
        }
    }

    // ---- epilogue: C tiles -> LDS (overwrites B area), coalesced store ----
    __syncthreads();
    float* o_w = (float*)smem + wave * OSLICE_WORDS;   // [p_local][o], stride 65
#pragma unroll
    for (int nt = 0; nt < 4; ++nt)
#pragma unroll
        for (int reg = 0; reg < 4; ++reg)
            o_w[(quad * 4 + reg) * 65 + nt * 16 + m] = acc[nt][reg];
    __syncthreads();

    const float* os = (const float*)smem;
#pragma unroll
    for (int j = tid; j < 64 * 128; j += 512) {
        int o = j >> 7;                  // wave-uniform per iteration
        int p = j & 127;
        int w2 = p >> 4, pl = p & 15;
        float v = os[w2 * OSLICE_WORDS + pl * 65 + o] + bias[o];
        out[(((size_t)(b * OH + o)) << 14) + (y << 7) + p] = v;
    }
}

extern "C" void kernel_launch(void* const* d_in, const int* in_sizes, int n_in,
                              void* d_out, int out_size, void* d_ws, size_t ws_size,
                              hipStream_t stream) {
    const float* x      = (const float*)d_in[0];
    const float* offset = (const float*)d_in[1];
    const float* weight = (const float*)d_in[2];
    const float* bias   = (const float*)d_in[3];
    float* out = (float*)d_out;

    unsigned short* xt  = (unsigned short*)d_ws;                           // 8.39 MB
    unsigned short* wtb = (unsigned short*)((char*)d_ws + (size_t)BH * HW * CH * 2);

    dcl_prep<<<1024 + 144, 256, 0, stream>>>(x, weight, xt, wtb);
    dcl_main<<<BH * HH, 512, 0, stream>>>(xt, offset, wtb, bias, out);
}